// Round 9
// baseline (277.653 us; speedup 1.0000x reference)
//
#include <hip/hip_runtime.h>

// AttentionBasedPooling: B=2048, F=32 (P=496 pairs), D=64, H=64.
// afm[b] = sum_p attn[b,p]*dot(x_i,x_j); attn = softmax_p of
// scores[p] = relu((x_i*x_j)@W1 + b1)@Ws + bs (bs cancels in softmax).
// R9: block-invariant prep (W1 fragment-ordered f16, transposed pair
// table, b1/Ws) hoisted into a one-time setup kernel writing d_ws; main
// kernel prologue = x staging + one coalesced 8KB ws->LDS copy. Pair
// codes per lane preloaded (2 dwordx4) -- no per-tile chain-head DS read.
// G=1, 2048 blocks, launch_bounds(256,8) -> 8 blocks/CU (R8 showed
// occupancy beats amortization). Tile body = verified R7/R8:
// mfma_f32_16x16x32_f16 swapped operands (h^T), ones-row s_p MFMA,
// packed-f32 epilogue, online max-free softmax.

#define F 32
#define D 64
#define H 64
#define P 496
#define RB 72   // f16 per xs row: 64 + 8 pad -> 144 B row stride

// d_ws layout
#define WS_W1F   0        // 4096 f16 = 8192 B, fragment order [ks][nt][l15][quad][j8]
#define WS_PTAB  8192     // 512 ints, transposed [l15][wid][tt]
#define WS_BW    10240    // 64 float2 {b1,Ws}

typedef __attribute__((ext_vector_type(8))) _Float16 f16x8;
typedef __attribute__((ext_vector_type(2))) _Float16 f16x2;
typedef __attribute__((ext_vector_type(4))) float f32x4;
typedef __attribute__((ext_vector_type(2))) float f32x2;

__global__ __launch_bounds__(256) void setup_kernel(
    const float* __restrict__ W1, const float* __restrict__ b1,
    const float* __restrict__ Ws, void* __restrict__ ws)
{
    _Float16* w1f = (_Float16*)((char*)ws + WS_W1F);
    int* ptab     = (int*)((char*)ws + WS_PTAB);
    float2* bwt   = (float2*)((char*)ws + WS_BW);
    const int tid = threadIdx.x;

    // W1 -> fragment order (verified R7 indexing), global scatter (once ever)
    const float4* w14 = (const float4*)W1;
    #pragma unroll
    for (int s = 0; s < 4; ++s) {
        int v = tid + s * 256;          // float4 index over W1[k][n]
        float4 w = w14[v];
        int k  = v >> 4;
        int ks = k >> 5, kq = (k >> 3) & 3, j8 = k & 7;
        int n0 = (v & 15) * 4;
        float e4[4] = { w.x, w.y, w.z, w.w };
        #pragma unroll
        for (int c = 0; c < 4; ++c) {
            int n = n0 + c, nt = n >> 4, l = n & 15;
            w1f[(((ks * 4 + nt) * 16 + l) * 4 + kq) * 8 + j8] = (_Float16)e4[c];
        }
    }
    // transposed pair table: tile t = wid + 4*tt handles pairs t*16+l15;
    // store code for (t,l15) at [(l15*4+wid)*8+tt] -> 8 contiguous ints/lane.
    for (int p = tid; p < 512; p += 256) {
        int i, j;
        if (p < P) {   // closed form, verified R4-R8
            i = (int)((63.0f - __builtin_sqrtf((float)(3969 - 8 * p))) * 0.5f);
            if (i * (63 - i) / 2 > p) --i;
            if ((i + 1) * (62 - i) / 2 <= p) ++i;
            j = i + 1 + (p - i * (63 - i) / 2);
        } else { i = 0; j = 0; }
        int code = (i * RB * 2) << 16 | (j * RB * 2);
        int tile = p >> 4, l = p & 15;
        ptab[((l * 4) + (tile & 3)) * 8 + (tile >> 2)] = code;
    }
    if (tid < H) bwt[tid] = make_float2(b1[tid], Ws[tid]);
}

__global__ __launch_bounds__(256, 8) void afm_kernel(
    const float* __restrict__ x, const void* __restrict__ ws,
    float* __restrict__ out)
{
    __shared__ _Float16 xs[F * RB];     // f16 x-tile (4608 B)
    __shared__ _Float16 w1f[4096];      // fragment-ordered W1 (8192 B)
    __shared__ float rednum[4], redden[4];

    const int tid  = threadIdx.x;
    const int b    = blockIdx.x;
    const int lane = tid & 63;
    const int wid  = tid >> 6;
    const int l15  = lane & 15;
    const int quad = lane >> 4;

    // ---- stage x[b] -> f16 LDS (2 coalesced float4 loads/thread) ----
    const float4* xb4 = (const float4*)(x + (size_t)b * (F * D));
    #pragma unroll
    for (int s = 0; s < 2; ++s) {
        int v = tid + s * 256;
        float4 w = xb4[v];
        int row = v >> 4, col = (v & 15) * 4;
        f16x2 lo = { (_Float16)w.x, (_Float16)w.y };
        f16x2 hi = { (_Float16)w.z, (_Float16)w.w };
        *(f16x2*)&xs[row * RB + col]     = lo;
        *(f16x2*)&xs[row * RB + col + 2] = hi;
    }
    // ---- copy fragment-ordered W1 ws->LDS (2 coalesced int4/thread) ----
    const int4* wsrc = (const int4*)((const char*)ws + WS_W1F);
    #pragma unroll
    for (int s = 0; s < 2; ++s) {
        int v = tid + s * 256;
        ((int4*)w1f)[v] = wsrc[v];
    }
    // ---- per-lane pair codes: 8 contiguous ints = 2 dwordx4 (L2-hot) ----
    const int4* pt4 = (const int4*)((const char*)ws + WS_PTAB);
    int4 ca = pt4[(l15 * 4 + wid) * 2 + 0];
    int4 cb = pt4[(l15 * 4 + wid) * 2 + 1];
    int codes[8] = { ca.x, ca.y, ca.z, ca.w, cb.x, cb.y, cb.z, cb.w };

    // ---- per-lane b1/Ws pairs for n = nt*16 + quad*4 + {0..3} (L2-hot) ----
    const float2* bwp = (const float2*)((const char*)ws + WS_BW);
    f32x2 b2[8], w2[8];
    #pragma unroll
    for (int nt = 0; nt < 4; ++nt) {
        const float2* src = &bwp[nt * 16 + quad * 4];
        float2 q0 = src[0], q1 = src[1], q2 = src[2], q3 = src[3];
        b2[nt*2+0] = (f32x2){q0.x, q1.x}; w2[nt*2+0] = (f32x2){q0.y, q1.y};
        b2[nt*2+1] = (f32x2){q2.x, q3.x}; w2[nt*2+1] = (f32x2){q2.y, q3.y};
    }
    __syncthreads();

    // ---- W1^T A-fragments from LDS: 8 conflict-free ds_read_b128 ----
    f16x8 wfrag[4][2];
    #pragma unroll
    for (int nt = 0; nt < 4; ++nt)
        #pragma unroll
        for (int ks = 0; ks < 2; ++ks)
            wfrag[nt][ks] = *(const f16x8*)&w1f[(((ks * 4 + nt) * 16 + l15) * 4 + quad) * 8];

    // ones-row A fragment: D_s[0][m] = sum_k B[k][m] = dot(x_i,x_j) at quad0
    const _Float16 onev = (l15 == 0) ? (_Float16)1.0f : (_Float16)0.0f;
    const f16x8 onesf = {onev, onev, onev, onev, onev, onev, onev, onev};

    const char* xsb = (const char*)xs;
    const int qb = quad << 4;
    float num = 0.f, den = 0.f;
    const f32x2 z2 = {0.f, 0.f};

    // ---- 8 tiles/wave: t = wid + 4*tt, pairs t*16 + l15 ----
    #pragma unroll 2
    for (int tt = 0; tt < 8; ++tt) {
        const int t  = wid + 4 * tt;
        const int code = codes[tt];
        const int io = ((unsigned)code) >> 16;
        const int jo = code & 0xFFFF;

        f16x8 xi0 = *(const f16x8*)(xsb + io + qb);        // k 0..31
        f16x8 xj0 = *(const f16x8*)(xsb + jo + qb);
        f16x8 xi1 = *(const f16x8*)(xsb + io + 64 + qb);   // k 32..63
        f16x8 xj1 = *(const f16x8*)(xsb + jo + 64 + qb);

        f16x8 A0 = xi0 * xj0;   // 4x v_pk_mul_f16
        f16x8 A1 = xi1 * xj1;

        f32x4 acc[4];
        #pragma unroll
        for (int nt = 0; nt < 4; ++nt) { f32x4 z = {0.f,0.f,0.f,0.f}; acc[nt] = z; }
        f32x4 accs = {0.f, 0.f, 0.f, 0.f};

        #pragma unroll
        for (int nt = 0; nt < 4; ++nt)
            acc[nt] = __builtin_amdgcn_mfma_f32_16x16x32_f16(wfrag[nt][0], A0, acc[nt], 0, 0, 0);
        accs = __builtin_amdgcn_mfma_f32_16x16x32_f16(onesf, A0, accs, 0, 0, 0);
        #pragma unroll
        for (int nt = 0; nt < 4; ++nt)
            acc[nt] = __builtin_amdgcn_mfma_f32_16x16x32_f16(wfrag[nt][1], A1, acc[nt], 0, 0, 0);
        accs = __builtin_amdgcn_mfma_f32_16x16x32_f16(onesf, A1, accs, 0, 0, 0);

        // packed epilogue: s = sum_n relu(h+b1)*Ws over this lane's 16 n's
        f32x2 s2 = {0.f, 0.f};
        #pragma unroll
        for (int nt = 0; nt < 4; ++nt) {
            f32x2 lo = {acc[nt][0], acc[nt][1]};
            f32x2 hi = {acc[nt][2], acc[nt][3]};
            lo += b2[nt*2+0]; hi += b2[nt*2+1];
            lo = __builtin_elementwise_max(lo, z2);
            hi = __builtin_elementwise_max(hi, z2);
            s2 = lo * w2[nt*2+0] + s2;
            s2 = hi * w2[nt*2+1] + s2;
        }
        float s = s2.x + s2.y;
        s += __shfl_xor(s, 16, 64);
        s += __shfl_xor(s, 32, 64);

        // online max-free softmax (verified R6-R8); tile 31 is dummy
        float e = __expf(s);
        e = (quad == 0 && t < 31) ? e : 0.f;
        num = fmaf(e, accs[0], num);   // accs[0] = dot(x_i,x_j) on quad0
        den += e;
    }

    // ---- reduce (quad0 lanes hold partials) ----
    #pragma unroll
    for (int off = 8; off >= 1; off >>= 1) {
        num += __shfl_xor(num, off, 64);
        den += __shfl_xor(den, off, 64);
    }
    if (lane == 0) { rednum[wid] = num; redden[wid] = den; }
    __syncthreads();
    if (tid == 0) {
        float nn = rednum[0] + rednum[1] + rednum[2] + rednum[3];
        float dd = redden[0] + redden[1] + redden[2] + redden[3];
        out[b] = nn / dd;
    }
}

extern "C" void kernel_launch(void* const* d_in, const int* in_sizes, int n_in,
                              void* d_out, int out_size, void* d_ws, size_t ws_size,
                              hipStream_t stream) {
    const float* x  = (const float*)d_in[0];
    const float* W1 = (const float*)d_in[1];
    const float* b1 = (const float*)d_in[2];
    const float* Ws = (const float*)d_in[3];
    float* out = (float*)d_out;
    const int B = in_sizes[0] / (F * D);  // 2048
    setup_kernel<<<1, 256, 0, stream>>>(W1, b1, Ws, d_ws);
    afm_kernel<<<B, 256, 0, stream>>>(x, d_ws, out);
}